// Round 5
// baseline (784.588 us; speedup 1.0000x reference)
//
#include <hip/hip_runtime.h>
#include <stdint.h>

// DSMIL forward on MI355X.
// R7 = R6 resubmit (R6 died to container-acquire failure; same precedent as
//   R3->R4 where identical resubmit ran clean. Schedule re-audited: vmcnt(2)
//   retirement traced per-wave through prologue+steady-state, overwrite
//   hazards >=2 barrier-pairs separated, no OOB, uniform barriers).
// R6: GEMM re-tiled for occupancy. R5 counters showed the 128KiB-LDS 8-phase
//   kernel latency-bound at 1 block/CU (MfmaUtil 20, VALU 13, Occ 18, 1.1TB/s).
//   Now: 256x256 tile, BK=32, LDS 64KiB double-buffered -> 2 blocks/CU; each
//   K-tile = 4 phases (C-quadrants, 8 MFMA each, frag reuse); 1 half-region
//   (8KB) staged per phase; uniform vmcnt(2) per phase end (each load retires
//   3 phases after issue). Cross-block TLP hides barrier/LDS/HBM stalls.
// Kept: T1 XCD swizzle, T2 XOR chunk swizzle (4-way cap at BK=32), T5 setprio,
//   MODE2 fused instance_pred, k_prep fusion, wide k_reduce.
// Pipeline: prep -> cast(x) -> GEMM1(relu) -> GEMM2(relu+ip) -> argmax ->
//   q_max -> t=q_max@w_q -> GEMM3(V) + k_logit -> reduce -> A+B -> C.

typedef unsigned short u16;
typedef __attribute__((ext_vector_type(8))) short short8;
typedef __attribute__((ext_vector_type(4))) float floatx4;

__device__ __forceinline__ float bf2f(u16 u) {
  union { unsigned u; float f; } x; x.u = ((unsigned)u) << 16; return x.f;
}
__device__ __forceinline__ u16 f2bf(float f) {
  union { float f; unsigned u; } x; x.f = f;
  return (u16)((x.u + 0x7fffu + ((x.u >> 16) & 1u)) >> 16);  // RNE
}
__device__ __forceinline__ unsigned ordf(float f) {
  union { float f; unsigned u; } x; x.f = f;
  return (x.u & 0x80000000u) ? ~x.u : (x.u | 0x80000000u);
}
__device__ __forceinline__ void gload16(const void* g, void* l) {
  __builtin_amdgcn_global_load_lds(
      (const __attribute__((address_space(1))) void*)g,
      (__attribute__((address_space(3))) void*)l, 16, 0, 0);
}

// ---------------- bf16 MFMA GEMM, C = A[M,K] * B[N,K]^T -------------------
// 256x256 tile, BK=32, 512 threads (8 waves, 2M x 4N), LDS 64 KiB (2 buf).
// Per K-tile t (buf=t&1): 4 phases = C-quadrants (0,0),(0,1),(1,1),(1,0);
// each phase: {ds_read new frags (a on MH change, b on NH change), stage one
// 8KB half-region of tile t+1 into buf^1, barrier, lgkmcnt(0), setprio(1),
// 8 MFMA, setprio(0), vmcnt(2), barrier}.
// Stage order per tile: ph1->Ah0(t+1) ph2->Bh0(t+1) ph3->Bh1(t+1) ph4->Ah1(t+1)
// First-need: t+1ph1 needs Ah0,Bh0 (retired by t-ph3/ph4 vmcnt(2));
// t+1ph2 needs Bh1 (retired end t+1ph1); t+1ph3 needs Ah1 (retired end t+1ph2).
// Every load waits 3 phases after issue -> HBM latency covered; 2 in flight.
// Overwrite of a region is issued >=2 barrier-pairs after its last read.
// LDS row maps (so each half-region serves both row-waves / all col-waves):
//   A half H LDS row q (0..127) holds global row (q&63) + (q>>6)*128 + H*64
//   B half H LDS row q holds global col (q&31) + ((q>>5)&3)*64 + H*32
// Read: A LDS row = MH*128 + wr*64 + f*16 + r15; B = NH*128 + wc*32 + g*16 + r15.
// Chunk swizzle: slot = chunk ^ (row&3) (store side: cg = c ^ (q&3)).
// MODE 0: relu+store. MODE 1: store. MODE 2: relu+store + fused instance_pred.

#define STG_A32(DST, H, T) do {                                         \
    const int _t = (T) < ktot ? (T) : (ktot - 1);                       \
    gload16(AgH[H] + _t * 32, (DST) + (H) * 4096 + tid * 8);            \
  } while (0)

#define STG_B32(DST, H, T) do {                                         \
    const int _t = (T) < ktot ? (T) : (ktot - 1);                       \
    gload16(BgH[H] + _t * 32, (DST) + (H) * 4096 + tid * 8);            \
  } while (0)

#define PH4(AB, BB, MH, NH, RA, RB, STG) do {                           \
    if (RA) {                                                           \
      _Pragma("unroll") for (int f = 0; f < 4; ++f)                     \
        a[f] = *(const short8*)((const char*)(AB) + (MH) * 8192 +       \
                                f * 1024 + offA);                       \
    }                                                                   \
    if (RB) {                                                           \
      _Pragma("unroll") for (int g = 0; g < 2; ++g)                     \
        b[g] = *(const short8*)((const char*)(BB) + (NH) * 8192 +       \
                                g * 1024 + offB);                       \
    }                                                                   \
    STG;                                                                \
    __builtin_amdgcn_s_barrier();                                       \
    asm volatile("s_waitcnt lgkmcnt(0)");                               \
    __builtin_amdgcn_sched_barrier(0);                                  \
    __builtin_amdgcn_s_setprio(1);                                      \
    _Pragma("unroll") for (int f = 0; f < 4; ++f)                       \
      _Pragma("unroll") for (int g = 0; g < 2; ++g)                     \
        acc[(MH) * 4 + f][(NH) * 2 + g] =                               \
            __builtin_amdgcn_mfma_f32_16x16x32_bf16(                    \
                a[f], b[g], acc[(MH) * 4 + f][(NH) * 2 + g], 0, 0, 0);  \
    __builtin_amdgcn_s_setprio(0);                                      \
    asm volatile("s_waitcnt vmcnt(2)");                                 \
    __builtin_amdgcn_s_barrier();                                       \
    __builtin_amdgcn_sched_barrier(0);                                  \
  } while (0)

template <int MODE>
__global__ __launch_bounds__(512) void gemm256(
    const u16* __restrict__ A, const u16* __restrict__ B,
    const float* __restrict__ bias, u16* __restrict__ O,
    int K, int ntiles, int ldo,
    const float* __restrict__ wfc, float* __restrict__ ipOut) {
  __shared__ __align__(16) u16 smem[32768];  // 64 KiB: As0|Bs0|As1|Bs1 x 16KB
  u16* const As0 = smem;
  u16* const Bs0 = smem + 8192;
  u16* const As1 = smem + 16384;
  u16* const Bs1 = smem + 24576;

  // XCD swizzle: consecutive j within an XCD share one A-panel (mt).
  const int xcd = blockIdx.x & 7;
  const int j = blockIdx.x >> 3;
  const int mstride = gridDim.x / (ntiles << 3);
  const int mt = xcd * mstride + j / ntiles;
  const int nt = j % ntiles;
  const int m0 = mt * 256, n0 = nt * 256;
  const int tid = threadIdx.x;
  const int lane = tid & 63;
  const int wid = tid >> 6;
  const int wr = wid >> 2;       // 0..1  (M)
  const int wc = wid & 3;        // 0..3  (N)
  const int wm = wr * 128, wn = wc * 64;

  // ---- staging addresses (row maps + chunk swizzle; dest linear tid*16B) ----
  const int q = tid >> 2;                    // 0..127 row within half-region
  const int cg = (tid & 3) ^ (q & 3);        // global 16B chunk for this lane
  const int gA = (q & 63) + ((q >> 6) & 1) * 128;
  const int gB = (q & 31) + ((q >> 5) & 3) * 64;
  const u16* AgH[2] = {A + (size_t)(m0 + gA) * K + cg * 8,
                       A + (size_t)(m0 + gA + 64) * K + cg * 8};
  const u16* BgH[2] = {B + (size_t)(n0 + gB) * K + cg * 8,
                       B + (size_t)(n0 + gB + 32) * K + cg * 8};

  // ---- fragment read offsets (bytes within a 16KB A/B region) ----
  const int r15 = lane & 15;
  const int c0 = lane >> 4;                  // k-chunk 0..3 (K=32 = 4x16B)
  const int sl = ((c0 ^ (r15 & 3)) * 16);
  const int offA = (wr * 64 + r15) * 64 + sl;
  const int offB = (wc * 32 + r15) * 64 + sl;

  floatx4 acc[8][4];
#pragma unroll
  for (int i = 0; i < 8; ++i)
#pragma unroll
    for (int jf = 0; jf < 4; ++jf) acc[i][jf] = (floatx4){0.f, 0.f, 0.f, 0.f};

  short8 a[4], b[2];

  const int ktot = K / 32;   // even for K=1024/1728
  const int NIT = ktot >> 1;

  // prologue: tile0's 4 half-regions in need-order; vmcnt(2) retires Ah0,Bh0.
  STG_A32(As0, 0, 0); STG_B32(Bs0, 0, 0); STG_B32(Bs0, 1, 0); STG_A32(As0, 1, 0);
  asm volatile("s_waitcnt vmcnt(2)");
  __builtin_amdgcn_s_barrier();
  __builtin_amdgcn_sched_barrier(0);

  for (int it = 0; it < NIT; ++it) {
    const int t1 = 2 * it + 1, t2 = 2 * it + 2;
    // tile 2it (buf0), stage tile 2it+1 -> buf1
    PH4(As0, Bs0, 0, 0, 1, 1, STG_A32(As1, 0, t1));
    PH4(As0, Bs0, 0, 1, 0, 1, STG_B32(Bs1, 0, t1));
    PH4(As0, Bs0, 1, 1, 1, 0, STG_B32(Bs1, 1, t1));
    PH4(As0, Bs0, 1, 0, 0, 1, STG_A32(As1, 1, t1));
    // tile 2it+1 (buf1), stage tile 2it+2 -> buf0
    PH4(As1, Bs1, 0, 0, 1, 1, STG_A32(As0, 0, t2));
    PH4(As1, Bs1, 0, 1, 0, 1, STG_B32(Bs0, 0, t2));
    PH4(As1, Bs1, 1, 1, 1, 0, STG_B32(Bs0, 1, t2));
    PH4(As1, Bs1, 1, 0, 0, 1, STG_A32(As0, 1, t2));
  }

  // C layout: col = lane&15, row = (lane>>4)*4 + reg  (m89/m91 verified)
  const int er = (lane >> 4) * 4;
  const int ec = lane & 15;
  if (MODE != 2) {
#pragma unroll
    for (int jf = 0; jf < 4; ++jf) {
      const int col = n0 + wn + jf * 16 + ec;
      const float bv = bias[col];
#pragma unroll
      for (int i = 0; i < 8; ++i) {
        const int row = m0 + wm + i * 16 + er;
#pragma unroll
        for (int r = 0; r < 4; ++r) {
          float v = acc[i][jf][r] + bv;
          if (MODE == 0) v = fmaxf(v, 0.f);
          O[(size_t)(row + r) * ldo + col] = f2bf(v);
        }
      }
    }
  } else {
    // relu + store + fused instance_pred partials over this block's 256 cols.
    float bvv[4], w0v[4], w1v[4];
#pragma unroll
    for (int jf = 0; jf < 4; ++jf) {
      const int col = n0 + wn + jf * 16 + ec;
      bvv[jf] = bias[col];
      w0v[jf] = wfc[col];
      w1v[jf] = wfc[1024 + col];
    }
#pragma unroll
    for (int i = 0; i < 8; ++i) {
      const int row = m0 + wm + i * 16 + er;
      float ps0[4] = {0.f, 0.f, 0.f, 0.f}, ps1[4] = {0.f, 0.f, 0.f, 0.f};
#pragma unroll
      for (int jf = 0; jf < 4; ++jf) {
        const int col = n0 + wn + jf * 16 + ec;
#pragma unroll
        for (int r = 0; r < 4; ++r) {
          float v = fmaxf(acc[i][jf][r] + bvv[jf], 0.f);
          O[(size_t)(row + r) * ldo + col] = f2bf(v);
          ps0[r] += v * w0v[jf];
          ps1[r] += v * w1v[jf];
        }
      }
      // reduce over the 16 lanes (xor 1,2,4,8) that share rows row..row+3
#pragma unroll
      for (int mm = 1; mm <= 8; mm <<= 1) {
#pragma unroll
        for (int r = 0; r < 4; ++r) {
          ps0[r] += __shfl_xor(ps0[r], mm, 64);
          ps1[r] += __shfl_xor(ps1[r], mm, 64);
        }
      }
      if ((lane & 15) == 0) {
#pragma unroll
        for (int r = 0; r < 4; ++r) {
          atomicAdd(&ipOut[(size_t)(row + r) * 2 + 0], ps0[r]);
          atomicAdd(&ipOut[(size_t)(row + r) * 2 + 1], ps1[r]);
        }
      }
    }
  }
}

// ---------------- glue kernels ---------------------------------------------
// One-shot prep: cast w1/w2/wv to bf16, init outIP=bfc, Bbuf=0, keys=0.
__global__ __launch_bounds__(256) void k_prep(
    const float* __restrict__ w1, const float* __restrict__ w2,
    const float* __restrict__ wv, u16* __restrict__ W1B, u16* __restrict__ W2B,
    u16* __restrict__ WVB, const float* __restrict__ bfc,
    float* __restrict__ outIP, float* __restrict__ Bbuf,
    unsigned long long* __restrict__ keys) {
  const int i = blockIdx.x * 256 + threadIdx.x;  // 0..966655 (float4 index)
  const float* s;
  unsigned long long* d;
  int k;
  if (i < 442368) { s = w1; d = (unsigned long long*)W1B; k = i; }
  else if (i < 704512) { s = w2; d = (unsigned long long*)W2B; k = i - 442368; }
  else { s = wv; d = (unsigned long long*)WVB; k = i - 704512; }
  float4 v = ((const float4*)s)[k];
  d[k] = (unsigned long long)f2bf(v.x) |
         ((unsigned long long)f2bf(v.y) << 16) |
         ((unsigned long long)f2bf(v.z) << 32) |
         ((unsigned long long)f2bf(v.w) << 48);
  if (i < 65536) outIP[i] = bfc[i & 1];
  if (i < 2048) Bbuf[i] = 0.f;
  if (i < 2) keys[i] = 0ull;
}

__global__ void k_cast(const float* __restrict__ s, u16* __restrict__ d, int n4) {
  int i = blockIdx.x * 256 + threadIdx.x;
  if (i >= n4) return;
  float4 v = ((const float4*)s)[i];
  unsigned long long o = (unsigned long long)f2bf(v.x) |
                         ((unsigned long long)f2bf(v.y) << 16) |
                         ((unsigned long long)f2bf(v.z) << 32) |
                         ((unsigned long long)f2bf(v.w) << 48);
  ((unsigned long long*)d)[i] = o;
}

// logits[row,c] = feat[row,:] . t[c,:]  (bias-free; const cancels in softmax)
__global__ __launch_bounds__(256) void k_logit(const u16* __restrict__ feat,
                                               const u16* __restrict__ tb,
                                               float* __restrict__ lg) {
  const int row = blockIdx.x * 4 + (threadIdx.x >> 6);
  const int lane = threadIdx.x & 63;
  const short8 f0 = *(const short8*)(feat + (size_t)row * 1024 + lane * 16);
  const short8 f1 = *(const short8*)(feat + (size_t)row * 1024 + lane * 16 + 8);
  const short8 t00 = *(const short8*)(tb + lane * 16);
  const short8 t01 = *(const short8*)(tb + lane * 16 + 8);
  const short8 t10 = *(const short8*)(tb + 1024 + lane * 16);
  const short8 t11 = *(const short8*)(tb + 1024 + lane * 16 + 8);
  float s0 = 0.f, s1 = 0.f;
#pragma unroll
  for (int t = 0; t < 8; ++t) {
    float fa = bf2f((u16)f0[t]), fb = bf2f((u16)f1[t]);
    s0 += fa * bf2f((u16)t00[t]) + fb * bf2f((u16)t01[t]);
    s1 += fa * bf2f((u16)t10[t]) + fb * bf2f((u16)t11[t]);
  }
#pragma unroll
  for (int off = 32; off > 0; off >>= 1) {
    s0 += __shfl_down(s0, off, 64);
    s1 += __shfl_down(s1, off, 64);
  }
  if (lane == 0) {
    lg[(size_t)row * 2 + 0] = s0;
    lg[(size_t)row * 2 + 1] = s1;
  }
}

// per-class argmax via encoded (ordered_val<<32)|(~idx) atomicMax
__global__ __launch_bounds__(256) void k_argmax(const float* __restrict__ ip,
                                                unsigned long long* __restrict__ keys) {
  float m0 = -1e30f, m1 = -1e30f;
  int i0 = 0, i1 = 0;
  for (int i = blockIdx.x * 256 + threadIdx.x; i < 32768; i += 256 * 64) {
    float v0 = ip[2 * i], v1 = ip[2 * i + 1];
    if (v0 > m0) { m0 = v0; i0 = i; }
    if (v1 > m1) { m1 = v1; i1 = i; }
  }
  unsigned long long k0 =
      ((unsigned long long)ordf(m0) << 32) | (0xFFFFFFFFu - (unsigned)i0);
  unsigned long long k1 =
      ((unsigned long long)ordf(m1) << 32) | (0xFFFFFFFFu - (unsigned)i1);
#pragma unroll
  for (int off = 32; off > 0; off >>= 1) {
    unsigned long long t0 = __shfl_down(k0, off, 64);
    unsigned long long t1 = __shfl_down(k1, off, 64);
    if (t0 > k0) k0 = t0;
    if (t1 > k1) k1 = t1;
  }
  __shared__ unsigned long long s0[4], s1[4];
  const int lane = threadIdx.x & 63, wv = threadIdx.x >> 6;
  if (lane == 0) { s0[wv] = k0; s1[wv] = k1; }
  __syncthreads();
  if (threadIdx.x == 0) {
    for (int w = 1; w < 4; ++w) {
      if (s0[w] > k0) k0 = s0[w];
      if (s1[w] > k1) k1 = s1[w];
    }
    atomicMax(keys + 0, k0);
    atomicMax(keys + 1, k1);
  }
}

// q_max[c,k] = feat[idx_c,:] . wq[k,:] + bq[k]; one wave per (c,k)
__global__ __launch_bounds__(256) void k_qmax(const u16* __restrict__ feat,
                                              const float* __restrict__ wq,
                                              const float* __restrict__ bq,
                                              const unsigned long long* __restrict__ keys,
                                              float* __restrict__ qmax) {
  const int gw = blockIdx.x * 4 + (threadIdx.x >> 6);  // 0..2047
  const int c = gw >> 10, k = gw & 1023;
  const int lane = threadIdx.x & 63;
  const int idx = (int)(0xFFFFFFFFu - (unsigned)(keys[c] & 0xFFFFFFFFull));
  const u16* fr = feat + (size_t)idx * 1024 + lane * 16;
  const float* wr = wq + (size_t)k * 1024 + lane * 16;
  float s = 0.f;
#pragma unroll
  for (int t = 0; t < 16; ++t) s += bf2f(fr[t]) * wr[t];
#pragma unroll
  for (int off = 32; off > 0; off >>= 1) s += __shfl_down(s, off, 64);
  if (lane == 0) qmax[c * 1024 + k] = s + bq[k];
}

// t[c,j] = sum_k qmax[c,k]*wq[k,j]. 32 blocks: kp=b>>2 (8 k-parts of 128),
// jb=b&3 (4 j-bands of 256). Plain-store partials (no init needed).
__global__ __launch_bounds__(256) void k_t(const float* __restrict__ wq,
                                           const float* __restrict__ qmax,
                                           float* __restrict__ tpart) {
  const int jb = blockIdx.x & 3, kp = blockIdx.x >> 2;
  const int jcol = jb * 256 + threadIdx.x;
  float s0 = 0.f, s1 = 0.f;
  for (int k = kp * 128; k < kp * 128 + 128; ++k) {
    float w = wq[(size_t)k * 1024 + jcol];
    s0 += qmax[k] * w;
    s1 += qmax[1024 + k] * w;
  }
  tpart[kp * 2048 + jcol] = s0;
  tpart[kp * 2048 + 1024 + jcol] = s1;
}

// reduce 8 k-partials -> bf16 t [2,1024]
__global__ __launch_bounds__(256) void k_tcast(const float* __restrict__ tpart,
                                               u16* __restrict__ tb) {
  const int i = blockIdx.x * 256 + threadIdx.x;  // 0..2047
  float s = 0.f;
#pragma unroll
  for (int kp = 0; kp < 8; ++kp) s += tpart[kp * 2048 + i];
  tb[i] = f2bf(s);
}

// per-class max + sum(exp((l-max)/32)) over 32768 rows; one 1024-thread block
__global__ __launch_bounds__(1024) void k_reduce(const float* __restrict__ lg,
                                                 float* __restrict__ ms) {
  __shared__ float r0[1024], r1[1024];
  const int tid = threadIdx.x;
  float m0 = -1e30f, m1 = -1e30f;
  for (int i = tid; i < 32768; i += 1024) {
    m0 = fmaxf(m0, lg[2 * i]);
    m1 = fmaxf(m1, lg[2 * i + 1]);
  }
  r0[tid] = m0; r1[tid] = m1;
  __syncthreads();
  for (int s = 512; s > 0; s >>= 1) {
    if (tid < s) {
      r0[tid] = fmaxf(r0[tid], r0[tid + s]);
      r1[tid] = fmaxf(r1[tid], r1[tid + s]);
    }
    __syncthreads();
  }
  m0 = r0[0]; m1 = r1[0];
  __syncthreads();
  float s0 = 0.f, s1 = 0.f;
  for (int i = tid; i < 32768; i += 1024) {
    s0 += __expf((lg[2 * i] - m0) * 0.03125f);
    s1 += __expf((lg[2 * i + 1] - m1) * 0.03125f);
  }
  r0[tid] = s0; r1[tid] = s1;
  __syncthreads();
  for (int s = 512; s > 0; s >>= 1) {
    if (tid < s) { r0[tid] += r0[tid + s]; r1[tid] += r1[tid + s]; }
    __syncthreads();
  }
  if (tid == 0) { ms[0] = m0; ms[1] = m1; ms[2] = r0[0]; ms[3] = r1[0]; }
}

// A[i,c] = exp((l-max)/32)/sum -> out; B[c,:] += sum_i A[i,c] V[i,:] (atomics)
__global__ __launch_bounds__(256) void k_ab(const float* __restrict__ lg,
                                            const float* __restrict__ ms,
                                            const u16* __restrict__ V,
                                            float* __restrict__ outA,
                                            float* __restrict__ Bbuf) {
  const int tid = threadIdx.x;
  const int row0 = blockIdx.x * 128;
  const float m0 = ms[0], m1 = ms[1];
  const float inv0 = 1.f / ms[2], inv1 = 1.f / ms[3];
  {
    const int r = row0 + (tid >> 1);
    const int c = tid & 1;
    outA[2 * r + c] =
        __expf((lg[2 * r + c] - (c ? m1 : m0)) * 0.03125f) * (c ? inv1 : inv0);
  }
  float p0[4] = {0, 0, 0, 0}, p1[4] = {0, 0, 0, 0};
  const int kb = tid * 4;
  for (int r = row0; r < row0 + 128; ++r) {
    const float a0 = __expf((lg[2 * r] - m0) * 0.03125f) * inv0;
    const float a1 = __expf((lg[2 * r + 1] - m1) * 0.03125f) * inv1;
    unsigned long long vv = *(const unsigned long long*)(V + (size_t)r * 1024 + kb);
    float f0 = bf2f((u16)vv), f1 = bf2f((u16)(vv >> 16));
    float f2 = bf2f((u16)(vv >> 32)), f3 = bf2f((u16)(vv >> 48));
    p0[0] += a0 * f0; p0[1] += a0 * f1; p0[2] += a0 * f2; p0[3] += a0 * f3;
    p1[0] += a1 * f0; p1[1] += a1 * f1; p1[2] += a1 * f2; p1[3] += a1 * f3;
  }
#pragma unroll
  for (int t = 0; t < 4; ++t) {
    atomicAdd(&Bbuf[kb + t], p0[t]);
    atomicAdd(&Bbuf[1024 + kb + t], p1[t]);
  }
}

// C[o] = sum_{i,k} wfcc[o,i,k]*B[i,k] + bfcc[o]; also copy B to out
__global__ __launch_bounds__(256) void k_c(const float* __restrict__ Bbuf,
                                           const float* __restrict__ wfcc,
                                           const float* __restrict__ bfcc,
                                           float* __restrict__ outC,
                                           float* __restrict__ outB) {
  __shared__ float r0[256], r1[256];
  const int tid = threadIdx.x;
  float s0 = 0.f, s1 = 0.f;
  for (int i = tid; i < 2048; i += 256) {
    float b = Bbuf[i];
    outB[i] = b;
    s0 += wfcc[i] * b;
    s1 += wfcc[2048 + i] * b;
  }
  r0[tid] = s0; r1[tid] = s1;
  __syncthreads();
  for (int s = 128; s > 0; s >>= 1) {
    if (tid < s) { r0[tid] += r0[tid + s]; r1[tid] += r1[tid + s]; }
    __syncthreads();
  }
  if (tid == 0) {
    outC[0] = r0[0] + bfcc[0];
    outC[1] = r1[0] + bfcc[1];
  }
}

extern "C" void kernel_launch(void* const* d_in, const int* in_sizes, int n_in,
                              void* d_out, int out_size, void* d_ws, size_t ws_size,
                              hipStream_t stream) {
  const float* x    = (const float*)d_in[0];
  const float* w1   = (const float*)d_in[1];
  const float* b1   = (const float*)d_in[2];
  const float* w2   = (const float*)d_in[3];
  const float* b2   = (const float*)d_in[4];
  const float* wfc  = (const float*)d_in[5];
  const float* bfc  = (const float*)d_in[6];
  const float* wq   = (const float*)d_in[7];
  const float* bq   = (const float*)d_in[8];
  const float* wv   = (const float*)d_in[9];
  const float* bv   = (const float*)d_in[10];
  const float* wfcc = (const float*)d_in[11];
  const float* bfcc = (const float*)d_in[12];

  float* out   = (float*)d_out;
  float* outIP = out;            // 65536
  float* outC  = out + 65536;    // 2
  float* outA  = out + 65538;    // 65536
  float* outB  = out + 131074;   // 2048

  char* ws = (char*)d_ws;
  u16* XB  = (u16*)(ws);                       // x bf16    113,246,208 B
  u16* HB  = (u16*)(ws + 113246208);           // h bf16, reused as V  67,108,864
  u16* FB  = (u16*)(ws + 180355072);           // feat bf16            67,108,864
  u16* W1B = (u16*)(ws + 247463936);           // w1 bf16 3,538,944 (dead after GEMM1)
  float* TPART = (float*)(ws + 247463936);     // k_t partials [8][2048] (reuses W1B)
  u16* TB  = (u16*)(ws + 247529472);           // t bf16 [2,1024] (reuses W1B)
  u16* W2B = (u16*)(ws + 251002880);           // w2 bf16               2,097,152
  u16* WVB = (u16*)(ws + 253100032);           // wv bf16               2,097,152
  float* LG = (float*)(ws + 255197184);        // logits [32768,2]        262,144
  float* QM = (float*)(ws + 255459328);        // q_max [2,1024]            8,192
  unsigned long long* KEYS = (unsigned long long*)(ws + 255467520);  // 16
  float* MS   = (float*)(ws + 255467536);      // max0,max1,sum0,sum1       16
  float* BBUF = (float*)(ws + 255467552);      // B accum [2,1024]        8,192

  k_prep<<<3776, 256, 0, stream>>>(w1, w2, wv, W1B, W2B, WVB, bfc, outIP,
                                   BBUF, KEYS);
  k_cast<<<55296, 256, 0, stream>>>(x, XB, 56623104 / 4);

  gemm256<0><<<512, 512, 0, stream>>>(XB, W1B, b1, HB, 1728, 4, 1024,
                                      nullptr, nullptr);
  gemm256<2><<<512, 512, 0, stream>>>(HB, W2B, b2, FB, 1024, 4, 1024,
                                      wfc, outIP);

  k_argmax<<<64, 256, 0, stream>>>(outIP, KEYS);
  k_qmax<<<512, 256, 0, stream>>>(FB, wq, bq, KEYS, QM);
  k_t<<<32, 256, 0, stream>>>(wq, QM, TPART);
  k_tcast<<<8, 256, 0, stream>>>(TPART, TB);

  gemm256<1><<<512, 512, 0, stream>>>(FB, WVB, bv, HB, 1024, 4, 1024,
                                      nullptr, nullptr);
  k_logit<<<8192, 256, 0, stream>>>(FB, TB, LG);

  k_reduce<<<1, 1024, 0, stream>>>(LG, MS);
  k_ab<<<256, 256, 0, stream>>>(LG, MS, HB, outA, BBUF);
  k_c<<<1, 256, 0, stream>>>(BBUF, wfcc, bfcc, outC, outB);
}

// Round 6
// 765.271 us; speedup vs baseline: 1.0252x; 1.0252x over previous
//
#include <hip/hip_runtime.h>
#include <stdint.h>

// DSMIL forward on MI355X.
// R8: revert K-loop to R5's verified 8-phase BK=64 schedule (R7's BK=32
//   4-phase regressed: 4-chunk swizzle reintroduced 1.2e7 bank conflicts and
//   occupancy is register-capped (~216 regs/wave) so 64KB LDS bought nothing).
//   NEW: coalesced epilogue via LDS bounce — the old epilogue was 128 scalar
//   2B stores/thread (WRITE_SIZE 98-122MB vs 64MB output = RMW partial lines).
//   Now: 2 passes; owner waves write bf16 C-half into [128][256] u16 LDS image
//   (chunk XOR swizzle), barrier, all threads ds_read_b128 + store_dwordx4.
// Kept: T1 XCD swizzle, T2 8-chunk XOR (0 conflicts, R5-verified), T3/T4
//   8-phase counted vmcnt(4), T5 setprio, MODE2 fused instance_pred, k_prep,
//   wide k_reduce.
// Pipeline: prep -> cast(x) -> GEMM1(relu) -> GEMM2(relu+ip) -> argmax ->
//   q_max -> t=q_max@w_q -> GEMM3(V) + k_logit -> reduce -> A+B -> C.

typedef unsigned short u16;
typedef __attribute__((ext_vector_type(8))) short short8;
typedef __attribute__((ext_vector_type(4))) float floatx4;

__device__ __forceinline__ float bf2f(u16 u) {
  union { unsigned u; float f; } x; x.u = ((unsigned)u) << 16; return x.f;
}
__device__ __forceinline__ u16 f2bf(float f) {
  union { float f; unsigned u; } x; x.f = f;
  return (u16)((x.u + 0x7fffu + ((x.u >> 16) & 1u)) >> 16);  // RNE
}
__device__ __forceinline__ unsigned ordf(float f) {
  union { float f; unsigned u; } x; x.f = f;
  return (x.u & 0x80000000u) ? ~x.u : (x.u | 0x80000000u);
}
__device__ __forceinline__ void gload16(const void* g, void* l) {
  __builtin_amdgcn_global_load_lds(
      (const __attribute__((address_space(1))) void*)g,
      (__attribute__((address_space(3))) void*)l, 16, 0, 0);
}

// ---------------- bf16 MFMA GEMM, C = A[M,K] * B[N,K]^T -------------------
// 256x256 tile, BK=64, 512 threads (8 waves, 2M x 4N), LDS 128 KiB (2 buf).
// 8 phases per 2 K-tiles (R5 schedule, verified): each phase {ds_read frag
// subtile, stage 1 half-tile (2x gload_lds), barrier, lgkmcnt(0), setprio(1),
// 16 MFMA, setprio(0), [vmcnt(4) at ph4/ph8], barrier}.
//   ph1:Ahi(t1)->buf1 ph2:Blo(t1)->buf1 ph3:Alo(t2)->buf0 ph4:Bhi(t2)->buf0+VM
//   ph5:Ahi(t2)->buf0 ph6:Blo(t2)->buf0 ph7:Alo(t3)->buf1 ph8:Bhi(t3)->buf1+VM
// LDS row permutations: A lr blocks {0,1,2,3}*64 hold global rows {0,2,1,3}*64;
// B permB(s) = (s&31)+((s>>5)&3)*64+(s>>7)*32. 16B chunks XOR'd slot=c^(row&7)
// -> conflict-free ds_read_b128 (R5 counter: 0 conflicts).
// Epilogue: LDS bounce (2 passes x {owner-wave u16 writes, barrier, all-thread
// ds_read_b128 + global_store_dwordx4}).
// MODE 0: relu+store. MODE 1: store. MODE 2: relu+store + fused instance_pred.

#define VMW4 asm volatile("s_waitcnt vmcnt(4)")
#define NOVM (void)0

#define STG_A(DST, H, T) do {                                           \
    const int _t = (T) < ktot ? (T) : (ktot - 1);                       \
    u16* _l = (DST) + (H) * 8192 + tid * 8;                             \
    gload16(AgA[(H) * 2] + _t * 64, _l);                                \
    gload16(AgA[(H) * 2 + 1] + _t * 64, _l + 4096);                     \
  } while (0)

#define STG_B(DST, H, T) do {                                           \
    const int _t = (T) < ktot ? (T) : (ktot - 1);                       \
    u16* _l = (DST) + (H) * 8192 + tid * 8;                             \
    gload16(BgB[(H) * 2] + _t * 64, _l);                                \
    gload16(BgB[(H) * 2 + 1] + _t * 64, _l + 4096);                     \
  } while (0)

#define PH(AB, BB, MH, NH, LA, LB, STG, VM) do {                        \
    if (LA) {                                                           \
      _Pragma("unroll") for (int f = 0; f < 4; ++f) {                   \
        const char* _p = (const char*)(AB) + (MH) * 16384 + f * 2048;   \
        a0[f] = *(const short8*)(_p + offA0);                           \
        a1[f] = *(const short8*)(_p + offA1);                           \
      }                                                                 \
    }                                                                   \
    if (LB) {                                                           \
      _Pragma("unroll") for (int g = 0; g < 2; ++g) {                   \
        const char* _p = (const char*)(BB) + (NH) * 16384 + g * 2048;   \
        b0[g] = *(const short8*)(_p + offB0);                           \
        b1[g] = *(const short8*)(_p + offB1);                           \
      }                                                                 \
    }                                                                   \
    STG;                                                                \
    __builtin_amdgcn_s_barrier();                                       \
    asm volatile("s_waitcnt lgkmcnt(0)");                               \
    __builtin_amdgcn_sched_barrier(0);                                  \
    __builtin_amdgcn_s_setprio(1);                                      \
    _Pragma("unroll") for (int f = 0; f < 4; ++f)                       \
      _Pragma("unroll") for (int g = 0; g < 2; ++g) {                   \
        acc[(MH) * 4 + f][(NH) * 2 + g] =                               \
            __builtin_amdgcn_mfma_f32_16x16x32_bf16(                    \
                a0[f], b0[g], acc[(MH) * 4 + f][(NH) * 2 + g], 0, 0, 0);\
        acc[(MH) * 4 + f][(NH) * 2 + g] =                               \
            __builtin_amdgcn_mfma_f32_16x16x32_bf16(                    \
                a1[f], b1[g], acc[(MH) * 4 + f][(NH) * 2 + g], 0, 0, 0);\
      }                                                                 \
    __builtin_amdgcn_s_setprio(0);                                      \
    VM;                                                                 \
    __builtin_amdgcn_s_barrier();                                       \
    __builtin_amdgcn_sched_barrier(0);                                  \
  } while (0)

template <int MODE>
__global__ __launch_bounds__(512) void gemm256(
    const u16* __restrict__ A, const u16* __restrict__ B,
    const float* __restrict__ bias, u16* __restrict__ O,
    int K, int ntiles, int ldo,
    const float* __restrict__ wfc, float* __restrict__ ipOut) {
  __shared__ __align__(16) u16 smem[65536];  // 128 KiB
  u16* const As0v = smem;
  u16* const Bs0v = smem + 16384;
  u16* const As1v = smem + 32768;
  u16* const Bs1v = smem + 49152;

  // XCD swizzle: consecutive j within an XCD share one A-panel (mt).
  const int xcd = blockIdx.x & 7;
  const int j = blockIdx.x >> 3;
  const int mstride = gridDim.x / (ntiles << 3);
  const int mt = xcd * mstride + j / ntiles;
  const int nt = j % ntiles;
  const int m0 = mt * 256, n0 = nt * 256;
  const int tid = threadIdx.x;
  const int lane = tid & 63;
  const int wid = tid >> 6;
  const int wr = wid >> 2;       // 0..1  (M)
  const int wc = wid & 3;        // 0..3  (N)
  const int wm = wr * 128, wn = wc * 64;

  // ---- staging addresses (per-thread; row permutation + chunk swizzle) ----
  const int q = tid >> 3;                    // 0..63 (row-in-64 group)
  const int cg = (tid & 7) ^ (q & 7);        // global 16B chunk for this lane
  const u16* AgA[4] = {                      // lr blocks -> global rows
      A + (size_t)(m0 + q) * K + cg * 8,     //   {0,2,1,3}*64 permutation
      A + (size_t)(m0 + q + 128) * K + cg * 8,
      A + (size_t)(m0 + q + 64) * K + cg * 8,
      A + (size_t)(m0 + q + 192) * K + cg * 8};
  auto permB = [](int s) { return (s & 31) + ((s >> 5) & 3) * 64 + (s >> 7) * 32; };
  const u16* BgB[4] = {
      B + (size_t)(n0 + permB(q)) * K + cg * 8,
      B + (size_t)(n0 + permB(q + 64)) * K + cg * 8,
      B + (size_t)(n0 + permB(q + 128)) * K + cg * 8,
      B + (size_t)(n0 + permB(q + 192)) * K + cg * 8};

  // ---- fragment read offsets (bytes within A/B region of a buffer) ----
  const int c0 = lane >> 4;                  // k-chunk within K=32 half
  const int sw = lane & 7;
  const int offA0 = ((wr ? 64 : 0) + (lane & 15)) * 128 + ((c0 ^ sw) * 16);
  const int offA1 = offA0 ^ 64;              // k-half 1 (chunk | 4)
  const int offB0 = (wc * 32 + (lane & 15)) * 128 + ((c0 ^ sw) * 16);
  const int offB1 = offB0 ^ 64;

  floatx4 acc[8][4];
#pragma unroll
  for (int i = 0; i < 8; ++i)
#pragma unroll
    for (int jf = 0; jf < 4; ++jf) acc[i][jf] = (floatx4){0.f, 0.f, 0.f, 0.f};

  short8 a0[4], a1[4], b0[2], b1[2];

  const int ktot = K / 64;
  const int NIT = ktot >> 1;

  // prologue: tile0 (all 4 regions) + Alo1,Bhi1; vmcnt(4) retires tile0.
  STG_A(As0v, 0, 0); STG_B(Bs0v, 1, 0); STG_A(As0v, 1, 0); STG_B(Bs0v, 0, 0);
  STG_A(As1v, 0, 1); STG_B(Bs1v, 1, 1);
  VMW4;
  __builtin_amdgcn_s_barrier();
  __builtin_amdgcn_sched_barrier(0);

  for (int it = 0; it < NIT; ++it) {
    const int t1 = 2 * it + 1, t2 = 2 * it + 2, t3 = 2 * it + 3;
    PH(As0v, Bs0v, 0, 0, 1, 1, STG_A(As1v, 1, t1), NOVM);
    PH(As0v, Bs0v, 0, 1, 0, 1, STG_B(Bs1v, 0, t1), NOVM);
    PH(As0v, Bs0v, 1, 1, 1, 0, STG_A(As0v, 0, t2), NOVM);
    PH(As0v, Bs0v, 1, 0, 0, 1, STG_B(Bs0v, 1, t2), VMW4);
    PH(As1v, Bs1v, 0, 0, 1, 1, STG_A(As0v, 1, t2), NOVM);
    PH(As1v, Bs1v, 0, 1, 0, 1, STG_B(Bs0v, 0, t2), NOVM);
    PH(As1v, Bs1v, 1, 1, 1, 0, STG_A(As1v, 0, t3), NOVM);
    PH(As1v, Bs1v, 1, 0, 0, 1, STG_B(Bs1v, 1, t3), VMW4);
  }

  if (ktot & 1) {  // tail tile (ktot-1) sits complete in buf0
#pragma unroll
    for (int mh = 0; mh < 2; ++mh) {
#pragma unroll
      for (int f = 0; f < 4; ++f) {
        const char* p = (const char*)As0v + mh * 16384 + f * 2048;
        a0[f] = *(const short8*)(p + offA0);
        a1[f] = *(const short8*)(p + offA1);
      }
#pragma unroll
      for (int nh = 0; nh < 2; ++nh) {
#pragma unroll
        for (int g = 0; g < 2; ++g) {
          const char* p = (const char*)Bs0v + nh * 16384 + g * 2048;
          b0[g] = *(const short8*)(p + offB0);
          b1[g] = *(const short8*)(p + offB1);
        }
#pragma unroll
        for (int f = 0; f < 4; ++f)
#pragma unroll
          for (int g = 0; g < 2; ++g) {
            acc[mh * 4 + f][nh * 2 + g] = __builtin_amdgcn_mfma_f32_16x16x32_bf16(
                a0[f], b0[g], acc[mh * 4 + f][nh * 2 + g], 0, 0, 0);
            acc[mh * 4 + f][nh * 2 + g] = __builtin_amdgcn_mfma_f32_16x16x32_bf16(
                a1[f], b1[g], acc[mh * 4 + f][nh * 2 + g], 0, 0, 0);
          }
      }
    }
  }

  // ---- epilogue: LDS-bounce coalesced C write --------------------------
  // acc C layout: col = lane&15, row = (lane>>4)*4 + reg (m89/m91 verified).
  // Pass p: waves with wr==p write their 128x256 bf16 half into smem image
  // [128 rows][256 u16] with 16B-chunk swizzle slot=(col>>3)^(row&31);
  // then all 512 threads read b128 and store dwordx4 (16B coalesced).
  const int er = (lane >> 4) * 4;
  const int ec = lane & 15;
  __syncthreads();  // all tail reads done before smem reuse
#pragma unroll
  for (int p = 0; p < 2; ++p) {
    if (wr == p) {
      float bvv[4], w0v[4], w1v[4];
#pragma unroll
      for (int jf = 0; jf < 4; ++jf) {
        const int col = n0 + wn + jf * 16 + ec;
        bvv[jf] = bias[col];
        if (MODE == 2) { w0v[jf] = wfc[col]; w1v[jf] = wfc[1024 + col]; }
      }
#pragma unroll
      for (int i = 0; i < 8; ++i) {
        float ps0[4] = {0.f, 0.f, 0.f, 0.f}, ps1[4] = {0.f, 0.f, 0.f, 0.f};
#pragma unroll
        for (int jf = 0; jf < 4; ++jf) {
          const int lcol = wn + jf * 16 + ec;
#pragma unroll
          for (int r = 0; r < 4; ++r) {
            float v = acc[i][jf][r] + bvv[jf];
            if (MODE != 1) v = fmaxf(v, 0.f);
            const int lrow = i * 16 + er + r;
            smem[lrow * 256 + (((lcol >> 3) ^ (lrow & 31)) << 3) + (lcol & 7)] =
                f2bf(v);
            if (MODE == 2) { ps0[r] += v * w0v[jf]; ps1[r] += v * w1v[jf]; }
          }
        }
        if (MODE == 2) {
#pragma unroll
          for (int mm = 1; mm <= 8; mm <<= 1) {
#pragma unroll
            for (int r = 0; r < 4; ++r) {
              ps0[r] += __shfl_xor(ps0[r], mm, 64);
              ps1[r] += __shfl_xor(ps1[r], mm, 64);
            }
          }
          if ((lane & 15) == 0) {
            const int row = m0 + wm + i * 16 + er;
#pragma unroll
            for (int r = 0; r < 4; ++r) {
              atomicAdd(&ipOut[(size_t)(row + r) * 2 + 0], ps0[r]);
              atomicAdd(&ipOut[(size_t)(row + r) * 2 + 1], ps1[r]);
            }
          }
        }
      }
    }
    __syncthreads();
    // all threads: 8 rounds x 16 rows; thread -> (row-in-16, chunk)
    const int ch = tid & 31;        // 16B chunk of the 512B row
    const int rg = tid >> 5;        // 0..15
#pragma unroll
    for (int k = 0; k < 8; ++k) {
      const int lrow = k * 16 + rg;
      const short8 v =
          *(const short8*)(smem + lrow * 256 + ((ch ^ (lrow & 31)) << 3));
      *(short8*)(O + (size_t)(m0 + p * 128 + lrow) * ldo + n0 + ch * 8) = v;
    }
    __syncthreads();
  }
}

// ---------------- glue kernels ---------------------------------------------
// One-shot prep: cast w1/w2/wv to bf16, init outIP=bfc, Bbuf=0, keys=0.
__global__ __launch_bounds__(256) void k_prep(
    const float* __restrict__ w1, const float* __restrict__ w2,
    const float* __restrict__ wv, u16* __restrict__ W1B, u16* __restrict__ W2B,
    u16* __restrict__ WVB, const float* __restrict__ bfc,
    float* __restrict__ outIP, float* __restrict__ Bbuf,
    unsigned long long* __restrict__ keys) {
  const int i = blockIdx.x * 256 + threadIdx.x;  // 0..966655 (float4 index)
  const float* s;
  unsigned long long* d;
  int k;
  if (i < 442368) { s = w1; d = (unsigned long long*)W1B; k = i; }
  else if (i < 704512) { s = w2; d = (unsigned long long*)W2B; k = i - 442368; }
  else { s = wv; d = (unsigned long long*)WVB; k = i - 704512; }
  float4 v = ((const float4*)s)[k];
  d[k] = (unsigned long long)f2bf(v.x) |
         ((unsigned long long)f2bf(v.y) << 16) |
         ((unsigned long long)f2bf(v.z) << 32) |
         ((unsigned long long)f2bf(v.w) << 48);
  if (i < 65536) outIP[i] = bfc[i & 1];
  if (i < 2048) Bbuf[i] = 0.f;
  if (i < 2) keys[i] = 0ull;
}

__global__ void k_cast(const float* __restrict__ s, u16* __restrict__ d, int n4) {
  int i = blockIdx.x * 256 + threadIdx.x;
  if (i >= n4) return;
  float4 v = ((const float4*)s)[i];
  unsigned long long o = (unsigned long long)f2bf(v.x) |
                         ((unsigned long long)f2bf(v.y) << 16) |
                         ((unsigned long long)f2bf(v.z) << 32) |
                         ((unsigned long long)f2bf(v.w) << 48);
  ((unsigned long long*)d)[i] = o;
}

// logits[row,c] = feat[row,:] . t[c,:]  (bias-free; const cancels in softmax)
__global__ __launch_bounds__(256) void k_logit(const u16* __restrict__ feat,
                                               const u16* __restrict__ tb,
                                               float* __restrict__ lg) {
  const int row = blockIdx.x * 4 + (threadIdx.x >> 6);
  const int lane = threadIdx.x & 63;
  const short8 f0 = *(const short8*)(feat + (size_t)row * 1024 + lane * 16);
  const short8 f1 = *(const short8*)(feat + (size_t)row * 1024 + lane * 16 + 8);
  const short8 t00 = *(const short8*)(tb + lane * 16);
  const short8 t01 = *(const short8*)(tb + lane * 16 + 8);
  const short8 t10 = *(const short8*)(tb + 1024 + lane * 16);
  const short8 t11 = *(const short8*)(tb + 1024 + lane * 16 + 8);
  float s0 = 0.f, s1 = 0.f;
#pragma unroll
  for (int t = 0; t < 8; ++t) {
    float fa = bf2f((u16)f0[t]), fb = bf2f((u16)f1[t]);
    s0 += fa * bf2f((u16)t00[t]) + fb * bf2f((u16)t01[t]);
    s1 += fa * bf2f((u16)t10[t]) + fb * bf2f((u16)t11[t]);
  }
#pragma unroll
  for (int off = 32; off > 0; off >>= 1) {
    s0 += __shfl_down(s0, off, 64);
    s1 += __shfl_down(s1, off, 64);
  }
  if (lane == 0) {
    lg[(size_t)row * 2 + 0] = s0;
    lg[(size_t)row * 2 + 1] = s1;
  }
}

// per-class argmax via encoded (ordered_val<<32)|(~idx) atomicMax
__global__ __launch_bounds__(256) void k_argmax(const float* __restrict__ ip,
                                                unsigned long long* __restrict__ keys) {
  float m0 = -1e30f, m1 = -1e30f;
  int i0 = 0, i1 = 0;
  for (int i = blockIdx.x * 256 + threadIdx.x; i < 32768; i += 256 * 64) {
    float v0 = ip[2 * i], v1 = ip[2 * i + 1];
    if (v0 > m0) { m0 = v0; i0 = i; }
    if (v1 > m1) { m1 = v1; i1 = i; }
  }
  unsigned long long k0 =
      ((unsigned long long)ordf(m0) << 32) | (0xFFFFFFFFu - (unsigned)i0);
  unsigned long long k1 =
      ((unsigned long long)ordf(m1) << 32) | (0xFFFFFFFFu - (unsigned)i1);
#pragma unroll
  for (int off = 32; off > 0; off >>= 1) {
    unsigned long long t0 = __shfl_down(k0, off, 64);
    unsigned long long t1 = __shfl_down(k1, off, 64);
    if (t0 > k0) k0 = t0;
    if (t1 > k1) k1 = t1;
  }
  __shared__ unsigned long long s0[4], s1[4];
  const int lane = threadIdx.x & 63, wv = threadIdx.x >> 6;
  if (lane == 0) { s0[wv] = k0; s1[wv] = k1; }
  __syncthreads();
  if (threadIdx.x == 0) {
    for (int w = 1; w < 4; ++w) {
      if (s0[w] > k0) k0 = s0[w];
      if (s1[w] > k1) k1 = s1[w];
    }
    atomicMax(keys + 0, k0);
    atomicMax(keys + 1, k1);
  }
}

// q_max[c,k] = feat[idx_c,:] . wq[k,:] + bq[k]; one wave per (c,k)
__global__ __launch_bounds__(256) void k_qmax(const u16* __restrict__ feat,
                                              const float* __restrict__ wq,
                                              const float* __restrict__ bq,
                                              const unsigned long long* __restrict__ keys,
                                              float* __restrict__ qmax) {
  const int gw = blockIdx.x * 4 + (threadIdx.x >> 6);  // 0..2047
  const int c = gw >> 10, k = gw & 1023;
  const int lane = threadIdx.x & 63;
  const int idx = (int)(0xFFFFFFFFu - (unsigned)(keys[c] & 0xFFFFFFFFull));
  const u16* fr = feat + (size_t)idx * 1024 + lane * 16;
  const float* wr = wq + (size_t)k * 1024 + lane * 16;
  float s = 0.f;
#pragma unroll
  for (int t = 0; t < 16; ++t) s += bf2f(fr[t]) * wr[t];
#pragma unroll
  for (int off = 32; off > 0; off >>= 1) s += __shfl_down(s, off, 64);
  if (lane == 0) qmax[c * 1024 + k] = s + bq[k];
}

// t[c,j] = sum_k qmax[c,k]*wq[k,j]. 32 blocks: kp=b>>2 (8 k-parts of 128),
// jb=b&3 (4 j-bands of 256). Plain-store partials (no init needed).
__global__ __launch_bounds__(256) void k_t(const float* __restrict__ wq,
                                           const float* __restrict__ qmax,
                                           float* __restrict__ tpart) {
  const int jb = blockIdx.x & 3, kp = blockIdx.x >> 2;
  const int jcol = jb * 256 + threadIdx.x;
  float s0 = 0.f, s1 = 0.f;
  for (int k = kp * 128; k < kp * 128 + 128; ++k) {
    float w = wq[(size_t)k * 1024 + jcol];
    s0 += qmax[k] * w;
    s1 += qmax[1024 + k] * w;
  }
  tpart[kp * 2048 + jcol] = s0;
  tpart[kp * 2048 + 1024 + jcol] = s1;
}

// reduce 8 k-partials -> bf16 t [2,1024]
__global__ __launch_bounds__(256) void k_tcast(const float* __restrict__ tpart,
                                               u16* __restrict__ tb) {
  const int i = blockIdx.x * 256 + threadIdx.x;  // 0..2047
  float s = 0.f;
#pragma unroll
  for (int kp = 0; kp < 8; ++kp) s += tpart[kp * 2048 + i];
  tb[i] = f2bf(s);
}

// per-class max + sum(exp((l-max)/32)) over 32768 rows; one 1024-thread block
__global__ __launch_bounds__(1024) void k_reduce(const float* __restrict__ lg,
                                                 float* __restrict__ ms) {
  __shared__ float r0[1024], r1[1024];
  const int tid = threadIdx.x;
  float m0 = -1e30f, m1 = -1e30f;
  for (int i = tid; i < 32768; i += 1024) {
    m0 = fmaxf(m0, lg[2 * i]);
    m1 = fmaxf(m1, lg[2 * i + 1]);
  }
  r0[tid] = m0; r1[tid] = m1;
  __syncthreads();
  for (int s = 512; s > 0; s >>= 1) {
    if (tid < s) {
      r0[tid] = fmaxf(r0[tid], r0[tid + s]);
      r1[tid] = fmaxf(r1[tid], r1[tid + s]);
    }
    __syncthreads();
  }
  m0 = r0[0]; m1 = r1[0];
  __syncthreads();
  float s0 = 0.f, s1 = 0.f;
  for (int i = tid; i < 32768; i += 1024) {
    s0 += __expf((lg[2 * i] - m0) * 0.03125f);
    s1 += __expf((lg[2 * i + 1] - m1) * 0.03125f);
  }
  r0[tid] = s0; r1[tid] = s1;
  __syncthreads();
  for (int s = 512; s > 0; s >>= 1) {
    if (tid < s) { r0[tid] += r0[tid + s]; r1[tid] += r1[tid + s]; }
    __syncthreads();
  }
  if (tid == 0) { ms[0] = m0; ms[1] = m1; ms[2] = r0[0]; ms[3] = r1[0]; }
}

// A[i,c] = exp((l-max)/32)/sum -> out; B[c,:] += sum_i A[i,c] V[i,:] (atomics)
__global__ __launch_bounds__(256) void k_ab(const float* __restrict__ lg,
                                            const float* __restrict__ ms,
                                            const u16* __restrict__ V,
                                            float* __restrict__ outA,
                                            float* __restrict__ Bbuf) {
  const int tid = threadIdx.x;
  const int row0 = blockIdx.x * 128;
  const float m0 = ms[0], m1 = ms[1];
  const float inv0 = 1.f / ms[2], inv1 = 1.f / ms[3];
  {
    const int r = row0 + (tid >> 1);
    const int c = tid & 1;
    outA[2 * r + c] =
        __expf((lg[2 * r + c] - (c ? m1 : m0)) * 0.03125f) * (c ? inv1 : inv0);
  }
  float p0[4] = {0, 0, 0, 0}, p1[4] = {0, 0, 0, 0};
  const int kb = tid * 4;
  for (int r = row0; r < row0 + 128; ++r) {
    const float a0 = __expf((lg[2 * r] - m0) * 0.03125f) * inv0;
    const float a1 = __expf((lg[2 * r + 1] - m1) * 0.03125f) * inv1;
    unsigned long long vv = *(const unsigned long long*)(V + (size_t)r * 1024 + kb);
    float f0 = bf2f((u16)vv), f1 = bf2f((u16)(vv >> 16));
    float f2 = bf2f((u16)(vv >> 32)), f3 = bf2f((u16)(vv >> 48));
    p0[0] += a0 * f0; p0[1] += a0 * f1; p0[2] += a0 * f2; p0[3] += a0 * f3;
    p1[0] += a1 * f0; p1[1] += a1 * f1; p1[2] += a1 * f2; p1[3] += a1 * f3;
  }
#pragma unroll
  for (int t = 0; t < 4; ++t) {
    atomicAdd(&Bbuf[kb + t], p0[t]);
    atomicAdd(&Bbuf[1024 + kb + t], p1[t]);
  }
}

// C[o] = sum_{i,k} wfcc[o,i,k]*B[i,k] + bfcc[o]; also copy B to out
__global__ __launch_bounds__(256) void k_c(const float* __restrict__ Bbuf,
                                           const float* __restrict__ wfcc,
                                           const float* __restrict__ bfcc,
                                           float* __restrict__ outC,
                                           float* __restrict__ outB) {
  __shared__ float r0[256], r1[256];
  const int tid = threadIdx.x;
  float s0 = 0.f, s1 = 0.f;
  for (int i = tid; i < 2048; i += 256) {
    float b = Bbuf[i];
    outB[i] = b;
    s0 += wfcc[i] * b;
    s1 += wfcc[2048 + i] * b;
  }
  r0[tid] = s0; r1[tid] = s1;
  __syncthreads();
  for (int s = 128; s > 0; s >>= 1) {
    if (tid < s) { r0[tid] += r0[tid + s]; r1[tid] += r1[tid + s]; }
    __syncthreads();
  }
  if (tid == 0) {
    outC[0] = r0[0] + bfcc[0];
    outC[1] = r1[0] + bfcc[1];
  }
}

extern "C" void kernel_launch(void* const* d_in, const int* in_sizes, int n_in,
                              void* d_out, int out_size, void* d_ws, size_t ws_size,
                              hipStream_t stream) {
  const float* x    = (const float*)d_in[0];
  const float* w1   = (const float*)d_in[1];
  const float* b1   = (const float*)d_in[2];
  const float* w2   = (const float*)d_in[3];
  const float* b2   = (const float*)d_in[4];
  const float* wfc  = (const float*)d_in[5];
  const float* bfc  = (const float*)d_in[6];
  const float* wq   = (const float*)d_in[7];
  const float* bq   = (const float*)d_in[8];
  const float* wv   = (const float*)d_in[9];
  const float* bv   = (const float*)d_in[10];
  const float* wfcc = (const float*)d_in[11];
  const float* bfcc = (const float*)d_in[12];

  float* out   = (float*)d_out;
  float* outIP = out;            // 65536
  float* outC  = out + 65536;    // 2
  float* outA  = out + 65538;    // 65536
  float* outB  = out + 131074;   // 2048

  char* ws = (char*)d_ws;
  u16* XB  = (u16*)(ws);                       // x bf16    113,246,208 B
  u16* HB  = (u16*)(ws + 113246208);           // h bf16, reused as V  67,108,864
  u16* FB  = (u16*)(ws + 180355072);           // feat bf16            67,108,864
  u16* W1B = (u16*)(ws + 247463936);           // w1 bf16 3,538,944 (dead after GEMM1)
  float* TPART = (float*)(ws + 247463936);     // k_t partials [8][2048] (reuses W1B)
  u16* TB  = (u16*)(ws + 247529472);           // t bf16 [2,1024] (reuses W1B)
  u16* W2B = (u16*)(ws + 251002880);           // w2 bf16               2,097,152
  u16* WVB = (u16*)(ws + 253100032);           // wv bf16               2,097,152
  float* LG = (float*)(ws + 255197184);        // logits [32768,2]        262,144
  float* QM = (float*)(ws + 255459328);        // q_max [2,1024]            8,192
  unsigned long long* KEYS = (unsigned long long*)(ws + 255467520);  // 16
  float* MS   = (float*)(ws + 255467536);      // max0,max1,sum0,sum1       16
  float* BBUF = (float*)(ws + 255467552);      // B accum [2,1024]        8,192

  k_prep<<<3776, 256, 0, stream>>>(w1, w2, wv, W1B, W2B, WVB, bfc, outIP,
                                   BBUF, KEYS);
  k_cast<<<55296, 256, 0, stream>>>(x, XB, 56623104 / 4);

  gemm256<0><<<512, 512, 0, stream>>>(XB, W1B, b1, HB, 1728, 4, 1024,
                                      nullptr, nullptr);
  gemm256<2><<<512, 512, 0, stream>>>(HB, W2B, b2, FB, 1024, 4, 1024,
                                      wfc, outIP);

  k_argmax<<<64, 256, 0, stream>>>(outIP, KEYS);
  k_qmax<<<512, 256, 0, stream>>>(FB, wq, bq, KEYS, QM);
  k_t<<<32, 256, 0, stream>>>(wq, QM, TPART);
  k_tcast<<<8, 256, 0, stream>>>(TPART, TB);

  gemm256<1><<<512, 512, 0, stream>>>(FB, WVB, bv, HB, 1024, 4, 1024,
                                      nullptr, nullptr);
  k_logit<<<8192, 256, 0, stream>>>(FB, TB, LG);

  k_reduce<<<1, 1024, 0, stream>>>(LG, MS);
  k_ab<<<256, 256, 0, stream>>>(LG, MS, HB, outA, BBUF);
  k_c<<<1, 256, 0, stream>>>(BBUF, wfcc, bfcc, outC, outB);
}

// Round 8
// 744.150 us; speedup vs baseline: 1.0543x; 1.0284x over previous
//
#include <hip/hip_runtime.h>
#include <stdint.h>

// DSMIL forward on MI355X.
// R10 = R9 resubmit (R9 died to container-acquire flake — 3rd occurrence,
//   both prior identical resubmits ran clean) + merged k_prep/k_cast launch.
// R9: R5 (best verified, 746us) + ONE GEMM change: A-staging loads use the NT
//   (non-temporal) cache policy (aux=2 = NT bit on gfx950 VMEM cpol).
//   Theory: GEMM staging demand ~900MiB/dispatch in ~140us = fetch ceiling;
//   the A-stream (no reuse) thrashes each XCD's 4MiB L2 and evicts the small
//   B panel, forcing BOTH operands to L3. NT on A keeps B L2-resident.
// GEMM: 256x256 / BK=64 / 8-wave / 8-phase, counted vmcnt(4) (T3+T4), 8-chunk
//   XOR LDS swizzle (T2, 0 conflicts verified), setprio (T5), XCD swizzle (T1).
// Pipeline: prep+cast(x) -> GEMM1(relu) -> GEMM2(relu+ip) -> argmax ->
//   q_max -> t=q_max@w_q -> GEMM3(V) + k_logit -> reduce -> A+B -> C.

typedef unsigned short u16;
typedef __attribute__((ext_vector_type(8))) short short8;
typedef __attribute__((ext_vector_type(4))) float floatx4;

__device__ __forceinline__ float bf2f(u16 u) {
  union { unsigned u; float f; } x; x.u = ((unsigned)u) << 16; return x.f;
}
__device__ __forceinline__ u16 f2bf(float f) {
  union { float f; unsigned u; } x; x.f = f;
  return (u16)((x.u + 0x7fffu + ((x.u >> 16) & 1u)) >> 16);  // RNE
}
__device__ __forceinline__ unsigned ordf(float f) {
  union { float f; unsigned u; } x; x.f = f;
  return (x.u & 0x80000000u) ? ~x.u : (x.u | 0x80000000u);
}
__device__ __forceinline__ void gload16(const void* g, void* l) {
  __builtin_amdgcn_global_load_lds(
      (const __attribute__((address_space(1))) void*)g,
      (__attribute__((address_space(3))) void*)l, 16, 0, 0);
}
// NT (non-temporal) variant for streamed A panels: cpol bit1 = NT on gfx950.
__device__ __forceinline__ void gload16nt(const void* g, void* l) {
  __builtin_amdgcn_global_load_lds(
      (const __attribute__((address_space(1))) void*)g,
      (__attribute__((address_space(3))) void*)l, 16, 0, 2);
}

// ---------------- bf16 MFMA GEMM, C = A[M,K] * B[N,K]^T -------------------
// 256x256 tile, BK=64, 512 threads (8 waves, 2M x 4N), LDS 128 KiB (2 buf).
// 8 phases per 2 K-tiles; each phase: {ds_read frag subtile, stage 1 half-tile
// (2x global_load_lds), barrier, lgkmcnt(0), setprio(1), 16 MFMA, setprio(0),
// [vmcnt(4) at ph4/ph8], barrier}.  Stage schedule (t1=2it+1,t2=2it+2,t3=2it+3):
//   ph1:Ahi(t1)->buf1 ph2:Blo(t1)->buf1 ph3:Alo(t2)->buf0 ph4:Bhi(t2)->buf0+VM
//   ph5:Ahi(t2)->buf0 ph6:Blo(t2)->buf0 ph7:Alo(t3)->buf1 ph8:Bhi(t3)->buf1+VM
// Every region: last-read completes (lgkmcnt between the phase's barriers)
// >=1 barrier-pair before its overwrite issues; staging loads retire via the
// vmcnt(4) >=1 barrier before their reader phase.
// LDS row permutations: A lr blocks {0,1,2,3}*64 hold global rows {0,2,1,3}*64;
// B permB(s) = (s&31)+((s>>5)&3)*64+(s>>7)*32. 16B chunks XOR'd slot=c^(row&7)
// -> conflict-free ds_read_b128 (R5 counter: 0 conflicts).
// MODE 0: relu+store. MODE 1: store. MODE 2: relu+store + fused instance_pred.

#define VMW4 asm volatile("s_waitcnt vmcnt(4)")
#define NOVM (void)0

#define STG_A(DST, H, T) do {                                           \
    const int _t = (T) < ktot ? (T) : (ktot - 1);                       \
    u16* _l = (DST) + (H) * 8192 + tid * 8;                             \
    gload16nt(AgA[(H) * 2] + _t * 64, _l);                              \
    gload16nt(AgA[(H) * 2 + 1] + _t * 64, _l + 4096);                   \
  } while (0)

#define STG_B(DST, H, T) do {                                           \
    const int _t = (T) < ktot ? (T) : (ktot - 1);                       \
    u16* _l = (DST) + (H) * 8192 + tid * 8;                             \
    gload16(BgB[(H) * 2] + _t * 64, _l);                                \
    gload16(BgB[(H) * 2 + 1] + _t * 64, _l + 4096);                     \
  } while (0)

#define PH(AB, BB, MH, NH, LA, LB, STG, VM) do {                        \
    if (LA) {                                                           \
      _Pragma("unroll") for (int f = 0; f < 4; ++f) {                   \
        const char* _p = (const char*)(AB) + (MH) * 16384 + f * 2048;   \
        a0[f] = *(const short8*)(_p + offA0);                           \
        a1[f] = *(const short8*)(_p + offA1);                           \
      }                                                                 \
    }                                                                   \
    if (LB) {                                                           \
      _Pragma("unroll") for (int g = 0; g < 2; ++g) {                   \
        const char* _p = (const char*)(BB) + (NH) * 16384 + g * 2048;   \
        b0[g] = *(const short8*)(_p + offB0);                           \
        b1[g] = *(const short8*)(_p + offB1);                           \
      }                                                                 \
    }                                                                   \
    STG;                                                                \
    __builtin_amdgcn_s_barrier();                                       \
    asm volatile("s_waitcnt lgkmcnt(0)");                               \
    __builtin_amdgcn_sched_barrier(0);                                  \
    __builtin_amdgcn_s_setprio(1);                                      \
    _Pragma("unroll") for (int f = 0; f < 4; ++f)                       \
      _Pragma("unroll") for (int g = 0; g < 2; ++g) {                   \
        acc[(MH) * 4 + f][(NH) * 2 + g] =                               \
            __builtin_amdgcn_mfma_f32_16x16x32_bf16(                    \
                a0[f], b0[g], acc[(MH) * 4 + f][(NH) * 2 + g], 0, 0, 0);\
        acc[(MH) * 4 + f][(NH) * 2 + g] =                               \
            __builtin_amdgcn_mfma_f32_16x16x32_bf16(                    \
                a1[f], b1[g], acc[(MH) * 4 + f][(NH) * 2 + g], 0, 0, 0);\
      }                                                                 \
    __builtin_amdgcn_s_setprio(0);                                      \
    VM;                                                                 \
    __builtin_amdgcn_s_barrier();                                       \
    __builtin_amdgcn_sched_barrier(0);                                  \
  } while (0)

template <int MODE>
__global__ __launch_bounds__(512) void gemm256(
    const u16* __restrict__ A, const u16* __restrict__ B,
    const float* __restrict__ bias, u16* __restrict__ O,
    int K, int ntiles, int ldo,
    const float* __restrict__ wfc, float* __restrict__ ipOut) {
  __shared__ __align__(16) u16 smem[65536];  // 128 KiB
  u16* const As0v = smem;
  u16* const Bs0v = smem + 16384;
  u16* const As1v = smem + 32768;
  u16* const Bs1v = smem + 49152;

  // XCD swizzle: consecutive j within an XCD share one A-panel (mt).
  const int xcd = blockIdx.x & 7;
  const int j = blockIdx.x >> 3;
  const int mstride = gridDim.x / (ntiles << 3);
  const int mt = xcd * mstride + j / ntiles;
  const int nt = j % ntiles;
  const int m0 = mt * 256, n0 = nt * 256;
  const int tid = threadIdx.x;
  const int lane = tid & 63;
  const int wid = tid >> 6;
  const int wr = wid >> 2;       // 0..1  (M)
  const int wc = wid & 3;        // 0..3  (N)
  const int wm = wr * 128, wn = wc * 64;

  // ---- staging addresses (per-thread; row permutation + chunk swizzle) ----
  const int q = tid >> 3;                    // 0..63 (row-in-64 group)
  const int cg = (tid & 7) ^ (q & 7);        // global 16B chunk for this lane
  const u16* AgA[4] = {                      // lr blocks -> global rows
      A + (size_t)(m0 + q) * K + cg * 8,     //   {0,2,1,3}*64 permutation
      A + (size_t)(m0 + q + 128) * K + cg * 8,
      A + (size_t)(m0 + q + 64) * K + cg * 8,
      A + (size_t)(m0 + q + 192) * K + cg * 8};
  auto permB = [](int s) { return (s & 31) + ((s >> 5) & 3) * 64 + (s >> 7) * 32; };
  const u16* BgB[4] = {
      B + (size_t)(n0 + permB(q)) * K + cg * 8,
      B + (size_t)(n0 + permB(q + 64)) * K + cg * 8,
      B + (size_t)(n0 + permB(q + 128)) * K + cg * 8,
      B + (size_t)(n0 + permB(q + 192)) * K + cg * 8};

  // ---- fragment read offsets (bytes within A/B region of a buffer) ----
  const int c0 = lane >> 4;                  // k-chunk within K=32 half
  const int sw = lane & 7;
  const int offA0 = ((wr ? 64 : 0) + (lane & 15)) * 128 + ((c0 ^ sw) * 16);
  const int offA1 = offA0 ^ 64;              // k-half 1 (chunk | 4)
  const int offB0 = (wc * 32 + (lane & 15)) * 128 + ((c0 ^ sw) * 16);
  const int offB1 = offB0 ^ 64;

  floatx4 acc[8][4];
#pragma unroll
  for (int i = 0; i < 8; ++i)
#pragma unroll
    for (int jf = 0; jf < 4; ++jf) acc[i][jf] = (floatx4){0.f, 0.f, 0.f, 0.f};

  short8 a0[4], a1[4], b0[2], b1[2];

  const int ktot = K / 64;
  const int NIT = ktot >> 1;

  // prologue: tile0 (all 4 regions) + Alo1,Bhi1; vmcnt(4) retires tile0.
  STG_A(As0v, 0, 0); STG_B(Bs0v, 1, 0); STG_A(As0v, 1, 0); STG_B(Bs0v, 0, 0);
  STG_A(As1v, 0, 1); STG_B(Bs1v, 1, 1);
  VMW4;
  __builtin_amdgcn_s_barrier();
  __builtin_amdgcn_sched_barrier(0);

  for (int it = 0; it < NIT; ++it) {
    const int t1 = 2 * it + 1, t2 = 2 * it + 2, t3 = 2 * it + 3;
    PH(As0v, Bs0v, 0, 0, 1, 1, STG_A(As1v, 1, t1), NOVM);
    PH(As0v, Bs0v, 0, 1, 0, 1, STG_B(Bs1v, 0, t1), NOVM);
    PH(As0v, Bs0v, 1, 1, 1, 0, STG_A(As0v, 0, t2), NOVM);
    PH(As0v, Bs0v, 1, 0, 0, 1, STG_B(Bs0v, 1, t2), VMW4);
    PH(As1v, Bs1v, 0, 0, 1, 1, STG_A(As0v, 1, t2), NOVM);
    PH(As1v, Bs1v, 0, 1, 0, 1, STG_B(Bs0v, 0, t2), NOVM);
    PH(As1v, Bs1v, 1, 1, 1, 0, STG_A(As1v, 0, t3), NOVM);
    PH(As1v, Bs1v, 1, 0, 0, 1, STG_B(Bs1v, 1, t3), VMW4);
  }

  if (ktot & 1) {  // tail tile (ktot-1) sits complete in buf0
#pragma unroll
    for (int mh = 0; mh < 2; ++mh) {
#pragma unroll
      for (int f = 0; f < 4; ++f) {
        const char* p = (const char*)As0v + mh * 16384 + f * 2048;
        a0[f] = *(const short8*)(p + offA0);
        a1[f] = *(const short8*)(p + offA1);
      }
#pragma unroll
      for (int nh = 0; nh < 2; ++nh) {
#pragma unroll
        for (int g = 0; g < 2; ++g) {
          const char* p = (const char*)Bs0v + nh * 16384 + g * 2048;
          b0[g] = *(const short8*)(p + offB0);
          b1[g] = *(const short8*)(p + offB1);
        }
#pragma unroll
        for (int f = 0; f < 4; ++f)
#pragma unroll
          for (int g = 0; g < 2; ++g) {
            acc[mh * 4 + f][nh * 2 + g] = __builtin_amdgcn_mfma_f32_16x16x32_bf16(
                a0[f], b0[g], acc[mh * 4 + f][nh * 2 + g], 0, 0, 0);
            acc[mh * 4 + f][nh * 2 + g] = __builtin_amdgcn_mfma_f32_16x16x32_bf16(
                a1[f], b1[g], acc[mh * 4 + f][nh * 2 + g], 0, 0, 0);
          }
      }
    }
  }

  // C layout: col = lane&15, row = (lane>>4)*4 + reg  (m89/m91 verified)
  const int er = (lane >> 4) * 4;
  const int ec = lane & 15;
  if (MODE != 2) {
#pragma unroll
    for (int jf = 0; jf < 4; ++jf) {
      const int col = n0 + wn + jf * 16 + ec;
      const float bv = bias[col];
#pragma unroll
      for (int i = 0; i < 8; ++i) {
        const int row = m0 + wm + i * 16 + er;
#pragma unroll
        for (int r = 0; r < 4; ++r) {
          float v = acc[i][jf][r] + bv;
          if (MODE == 0) v = fmaxf(v, 0.f);
          O[(size_t)(row + r) * ldo + col] = f2bf(v);
        }
      }
    }
  } else {
    // relu + store + fused instance_pred partials over this block's 256 cols.
    float bvv[4], w0v[4], w1v[4];
#pragma unroll
    for (int jf = 0; jf < 4; ++jf) {
      const int col = n0 + wn + jf * 16 + ec;
      bvv[jf] = bias[col];
      w0v[jf] = wfc[col];
      w1v[jf] = wfc[1024 + col];
    }
#pragma unroll
    for (int i = 0; i < 8; ++i) {
      const int row = m0 + wm + i * 16 + er;
      float ps0[4] = {0.f, 0.f, 0.f, 0.f}, ps1[4] = {0.f, 0.f, 0.f, 0.f};
#pragma unroll
      for (int jf = 0; jf < 4; ++jf) {
        const int col = n0 + wn + jf * 16 + ec;
#pragma unroll
        for (int r = 0; r < 4; ++r) {
          float v = fmaxf(acc[i][jf][r] + bvv[jf], 0.f);
          O[(size_t)(row + r) * ldo + col] = f2bf(v);
          ps0[r] += v * w0v[jf];
          ps1[r] += v * w1v[jf];
        }
      }
      // reduce over the 16 lanes (xor 1,2,4,8) that share rows row..row+3
#pragma unroll
      for (int mm = 1; mm <= 8; mm <<= 1) {
#pragma unroll
        for (int r = 0; r < 4; ++r) {
          ps0[r] += __shfl_xor(ps0[r], mm, 64);
          ps1[r] += __shfl_xor(ps1[r], mm, 64);
        }
      }
      if ((lane & 15) == 0) {
#pragma unroll
        for (int r = 0; r < 4; ++r) {
          atomicAdd(&ipOut[(size_t)(row + r) * 2 + 0], ps0[r]);
          atomicAdd(&ipOut[(size_t)(row + r) * 2 + 1], ps1[r]);
        }
      }
    }
  }
}

// ---------------- glue kernels ---------------------------------------------
// Merged prep: blocks [0,55296) cast x; blocks [55296,59072) cast w1/w2/wv,
// init outIP=bfc, Bbuf=0, keys=0. All outputs disjoint, no dependencies.
__global__ __launch_bounds__(256) void k_prepcast(
    const float* __restrict__ x, u16* __restrict__ XB,
    const float* __restrict__ w1, const float* __restrict__ w2,
    const float* __restrict__ wv, u16* __restrict__ W1B, u16* __restrict__ W2B,
    u16* __restrict__ WVB, const float* __restrict__ bfc,
    float* __restrict__ outIP, float* __restrict__ Bbuf,
    unsigned long long* __restrict__ keys) {
  if (blockIdx.x < 55296) {
    const int i = blockIdx.x * 256 + threadIdx.x;  // < 14155776 exactly
    float4 v = ((const float4*)x)[i];
    ((unsigned long long*)XB)[i] =
        (unsigned long long)f2bf(v.x) | ((unsigned long long)f2bf(v.y) << 16) |
        ((unsigned long long)f2bf(v.z) << 32) |
        ((unsigned long long)f2bf(v.w) << 48);
    return;
  }
  const int i = (blockIdx.x - 55296) * 256 + threadIdx.x;  // 0..966655
  const float* s;
  unsigned long long* d;
  int k;
  if (i < 442368) { s = w1; d = (unsigned long long*)W1B; k = i; }
  else if (i < 704512) { s = w2; d = (unsigned long long*)W2B; k = i - 442368; }
  else { s = wv; d = (unsigned long long*)WVB; k = i - 704512; }
  float4 v = ((const float4*)s)[k];
  d[k] = (unsigned long long)f2bf(v.x) |
         ((unsigned long long)f2bf(v.y) << 16) |
         ((unsigned long long)f2bf(v.z) << 32) |
         ((unsigned long long)f2bf(v.w) << 48);
  if (i < 65536) outIP[i] = bfc[i & 1];
  if (i < 2048) Bbuf[i] = 0.f;
  if (i < 2) keys[i] = 0ull;
}

// logits[row,c] = feat[row,:] . t[c,:]  (bias-free; const cancels in softmax)
__global__ __launch_bounds__(256) void k_logit(const u16* __restrict__ feat,
                                               const u16* __restrict__ tb,
                                               float* __restrict__ lg) {
  const int row = blockIdx.x * 4 + (threadIdx.x >> 6);
  const int lane = threadIdx.x & 63;
  const short8 f0 = *(const short8*)(feat + (size_t)row * 1024 + lane * 16);
  const short8 f1 = *(const short8*)(feat + (size_t)row * 1024 + lane * 16 + 8);
  const short8 t00 = *(const short8*)(tb + lane * 16);
  const short8 t01 = *(const short8*)(tb + lane * 16 + 8);
  const short8 t10 = *(const short8*)(tb + 1024 + lane * 16);
  const short8 t11 = *(const short8*)(tb + 1024 + lane * 16 + 8);
  float s0 = 0.f, s1 = 0.f;
#pragma unroll
  for (int t = 0; t < 8; ++t) {
    float fa = bf2f((u16)f0[t]), fb = bf2f((u16)f1[t]);
    s0 += fa * bf2f((u16)t00[t]) + fb * bf2f((u16)t01[t]);
    s1 += fa * bf2f((u16)t10[t]) + fb * bf2f((u16)t11[t]);
  }
#pragma unroll
  for (int off = 32; off > 0; off >>= 1) {
    s0 += __shfl_down(s0, off, 64);
    s1 += __shfl_down(s1, off, 64);
  }
  if (lane == 0) {
    lg[(size_t)row * 2 + 0] = s0;
    lg[(size_t)row * 2 + 1] = s1;
  }
}

// per-class argmax via encoded (ordered_val<<32)|(~idx) atomicMax
__global__ __launch_bounds__(256) void k_argmax(const float* __restrict__ ip,
                                                unsigned long long* __restrict__ keys) {
  float m0 = -1e30f, m1 = -1e30f;
  int i0 = 0, i1 = 0;
  for (int i = blockIdx.x * 256 + threadIdx.x; i < 32768; i += 256 * 64) {
    float v0 = ip[2 * i], v1 = ip[2 * i + 1];
    if (v0 > m0) { m0 = v0; i0 = i; }
    if (v1 > m1) { m1 = v1; i1 = i; }
  }
  unsigned long long k0 =
      ((unsigned long long)ordf(m0) << 32) | (0xFFFFFFFFu - (unsigned)i0);
  unsigned long long k1 =
      ((unsigned long long)ordf(m1) << 32) | (0xFFFFFFFFu - (unsigned)i1);
#pragma unroll
  for (int off = 32; off > 0; off >>= 1) {
    unsigned long long t0 = __shfl_down(k0, off, 64);
    unsigned long long t1 = __shfl_down(k1, off, 64);
    if (t0 > k0) k0 = t0;
    if (t1 > k1) k1 = t1;
  }
  __shared__ unsigned long long s0[4], s1[4];
  const int lane = threadIdx.x & 63, wv = threadIdx.x >> 6;
  if (lane == 0) { s0[wv] = k0; s1[wv] = k1; }
  __syncthreads();
  if (threadIdx.x == 0) {
    for (int w = 1; w < 4; ++w) {
      if (s0[w] > k0) k0 = s0[w];
      if (s1[w] > k1) k1 = s1[w];
    }
    atomicMax(keys + 0, k0);
    atomicMax(keys + 1, k1);
  }
}

// q_max[c,k] = feat[idx_c,:] . wq[k,:] + bq[k]; one wave per (c,k)
__global__ __launch_bounds__(256) void k_qmax(const u16* __restrict__ feat,
                                              const float* __restrict__ wq,
                                              const float* __restrict__ bq,
                                              const unsigned long long* __restrict__ keys,
                                              float* __restrict__ qmax) {
  const int gw = blockIdx.x * 4 + (threadIdx.x >> 6);  // 0..2047
  const int c = gw >> 10, k = gw & 1023;
  const int lane = threadIdx.x & 63;
  const int idx = (int)(0xFFFFFFFFu - (unsigned)(keys[c] & 0xFFFFFFFFull));
  const u16* fr = feat + (size_t)idx * 1024 + lane * 16;
  const float* wr = wq + (size_t)k * 1024 + lane * 16;
  float s = 0.f;
#pragma unroll
  for (int t = 0; t < 16; ++t) s += bf2f(fr[t]) * wr[t];
#pragma unroll
  for (int off = 32; off > 0; off >>= 1) s += __shfl_down(s, off, 64);
  if (lane == 0) qmax[c * 1024 + k] = s + bq[k];
}

// t[c,j] = sum_k qmax[c,k]*wq[k,j]. 32 blocks: kp=b>>2 (8 k-parts of 128),
// jb=b&3 (4 j-bands of 256). Plain-store partials (no init needed).
__global__ __launch_bounds__(256) void k_t(const float* __restrict__ wq,
                                           const float* __restrict__ qmax,
                                           float* __restrict__ tpart) {
  const int jb = blockIdx.x & 3, kp = blockIdx.x >> 2;
  const int jcol = jb * 256 + threadIdx.x;
  float s0 = 0.f, s1 = 0.f;
  for (int k = kp * 128; k < kp * 128 + 128; ++k) {
    float w = wq[(size_t)k * 1024 + jcol];
    s0 += qmax[k] * w;
    s1 += qmax[1024 + k] * w;
  }
  tpart[kp * 2048 + jcol] = s0;
  tpart[kp * 2048 + 1024 + jcol] = s1;
}

// reduce 8 k-partials -> bf16 t [2,1024]
__global__ __launch_bounds__(256) void k_tcast(const float* __restrict__ tpart,
                                               u16* __restrict__ tb) {
  const int i = blockIdx.x * 256 + threadIdx.x;  // 0..2047
  float s = 0.f;
#pragma unroll
  for (int kp = 0; kp < 8; ++kp) s += tpart[kp * 2048 + i];
  tb[i] = f2bf(s);
}

// per-class max + sum(exp((l-max)/32)) over 32768 rows; one 1024-thread block
__global__ __launch_bounds__(1024) void k_reduce(const float* __restrict__ lg,
                                                 float* __restrict__ ms) {
  __shared__ float r0[1024], r1[1024];
  const int tid = threadIdx.x;
  float m0 = -1e30f, m1 = -1e30f;
  for (int i = tid; i < 32768; i += 1024) {
    m0 = fmaxf(m0, lg[2 * i]);
    m1 = fmaxf(m1, lg[2 * i + 1]);
  }
  r0[tid] = m0; r1[tid] = m1;
  __syncthreads();
  for (int s = 512; s > 0; s >>= 1) {
    if (tid < s) {
      r0[tid] = fmaxf(r0[tid], r0[tid + s]);
      r1[tid] = fmaxf(r1[tid], r1[tid + s]);
    }
    __syncthreads();
  }
  m0 = r0[0]; m1 = r1[0];
  __syncthreads();
  float s0 = 0.f, s1 = 0.f;
  for (int i = tid; i < 32768; i += 1024) {
    s0 += __expf((lg[2 * i] - m0) * 0.03125f);
    s1 += __expf((lg[2 * i + 1] - m1) * 0.03125f);
  }
  r0[tid] = s0; r1[tid] = s1;
  __syncthreads();
  for (int s = 512; s > 0; s >>= 1) {
    if (tid < s) { r0[tid] += r0[tid + s]; r1[tid] += r1[tid + s]; }
    __syncthreads();
  }
  if (tid == 0) { ms[0] = m0; ms[1] = m1; ms[2] = r0[0]; ms[3] = r1[0]; }
}

// A[i,c] = exp((l-max)/32)/sum -> out; B[c,:] += sum_i A[i,c] V[i,:] (atomics)
__global__ __launch_bounds__(256) void k_ab(const float* __restrict__ lg,
                                            const float* __restrict__ ms,
                                            const u16* __restrict__ V,
                                            float* __restrict__ outA,
                                            float* __restrict__ Bbuf) {
  const int tid = threadIdx.x;
  const int row0 = blockIdx.x * 128;
  const float m0 = ms[0], m1 = ms[1];
  const float inv0 = 1.f / ms[2], inv1 = 1.f / ms[3];
  {
    const int r = row0 + (tid >> 1);
    const int c = tid & 1;
    outA[2 * r + c] =
        __expf((lg[2 * r + c] - (c ? m1 : m0)) * 0.03125f) * (c ? inv1 : inv0);
  }
  float p0[4] = {0, 0, 0, 0}, p1[4] = {0, 0, 0, 0};
  const int kb = tid * 4;
  for (int r = row0; r < row0 + 128; ++r) {
    const float a0 = __expf((lg[2 * r] - m0) * 0.03125f) * inv0;
    const float a1 = __expf((lg[2 * r + 1] - m1) * 0.03125f) * inv1;
    unsigned long long vv = *(const unsigned long long*)(V + (size_t)r * 1024 + kb);
    float f0 = bf2f((u16)vv), f1 = bf2f((u16)(vv >> 16));
    float f2 = bf2f((u16)(vv >> 32)), f3 = bf2f((u16)(vv >> 48));
    p0[0] += a0 * f0; p0[1] += a0 * f1; p0[2] += a0 * f2; p0[3] += a0 * f3;
    p1[0] += a1 * f0; p1[1] += a1 * f1; p1[2] += a1 * f2; p1[3] += a1 * f3;
  }
#pragma unroll
  for (int t = 0; t < 4; ++t) {
    atomicAdd(&Bbuf[kb + t], p0[t]);
    atomicAdd(&Bbuf[1024 + kb + t], p1[t]);
  }
}

// C[o] = sum_{i,k} wfcc[o,i,k]*B[i,k] + bfcc[o]; also copy B to out
__global__ __launch_bounds__(256) void k_c(const float* __restrict__ Bbuf,
                                           const float* __restrict__ wfcc,
                                           const float* __restrict__ bfcc,
                                           float* __restrict__ outC,
                                           float* __restrict__ outB) {
  __shared__ float r0[256], r1[256];
  const int tid = threadIdx.x;
  float s0 = 0.f, s1 = 0.f;
  for (int i = tid; i < 2048; i += 256) {
    float b = Bbuf[i];
    outB[i] = b;
    s0 += wfcc[i] * b;
    s1 += wfcc[2048 + i] * b;
  }
  r0[tid] = s0; r1[tid] = s1;
  __syncthreads();
  for (int s = 128; s > 0; s >>= 1) {
    if (tid < s) { r0[tid] += r0[tid + s]; r1[tid] += r1[tid + s]; }
    __syncthreads();
  }
  if (tid == 0) {
    outC[0] = r0[0] + bfcc[0];
    outC[1] = r1[0] + bfcc[1];
  }
}

extern "C" void kernel_launch(void* const* d_in, const int* in_sizes, int n_in,
                              void* d_out, int out_size, void* d_ws, size_t ws_size,
                              hipStream_t stream) {
  const float* x    = (const float*)d_in[0];
  const float* w1   = (const float*)d_in[1];
  const float* b1   = (const float*)d_in[2];
  const float* w2   = (const float*)d_in[3];
  const float* b2   = (const float*)d_in[4];
  const float* wfc  = (const float*)d_in[5];
  const float* bfc  = (const float*)d_in[6];
  const float* wq   = (const float*)d_in[7];
  const float* bq   = (const float*)d_in[8];
  const float* wv   = (const float*)d_in[9];
  const float* bv   = (const float*)d_in[10];
  const float* wfcc = (const float*)d_in[11];
  const float* bfcc = (const float*)d_in[12];

  float* out   = (float*)d_out;
  float* outIP = out;            // 65536
  float* outC  = out + 65536;    // 2
  float* outA  = out + 65538;    // 65536
  float* outB  = out + 131074;   // 2048

  char* ws = (char*)d_ws;
  u16* XB  = (u16*)(ws);                       // x bf16    113,246,208 B
  u16* HB  = (u16*)(ws + 113246208);           // h bf16, reused as V  67,108,864
  u16* FB  = (u16*)(ws + 180355072);           // feat bf16            67,108,864
  u16* W1B = (u16*)(ws + 247463936);           // w1 bf16 3,538,944 (dead after GEMM1)
  float* TPART = (float*)(ws + 247463936);     // k_t partials [8][2048] (reuses W1B)
  u16* TB  = (u16*)(ws + 247529472);           // t bf16 [2,1024] (reuses W1B)
  u16* W2B = (u16*)(ws + 251002880);           // w2 bf16               2,097,152
  u16* WVB = (u16*)(ws + 253100032);           // wv bf16               2,097,152
  float* LG = (float*)(ws + 255197184);        // logits [32768,2]        262,144
  float* QM = (float*)(ws + 255459328);        // q_max [2,1024]            8,192
  unsigned long long* KEYS = (unsigned long long*)(ws + 255467520);  // 16
  float* MS   = (float*)(ws + 255467536);      // max0,max1,sum0,sum1       16
  float* BBUF = (float*)(ws + 255467552);      // B accum [2,1024]        8,192

  k_prepcast<<<59072, 256, 0, stream>>>(x, XB, w1, w2, wv, W1B, W2B, WVB,
                                        bfc, outIP, BBUF, KEYS);

  gemm256<0><<<512, 512, 0, stream>>>(XB, W1B, b1, HB, 1728, 4, 1024,
                                      nullptr, nullptr);
  gemm256<2><<<512, 512, 0, stream>>>(HB, W2B, b2, FB, 1024, 4, 1024,
                                      wfc, outIP);

  k_argmax<<<64, 256, 0, stream>>>(outIP, KEYS);
  k_qmax<<<512, 256, 0, stream>>>(FB, wq, bq, KEYS, QM);
  k_t<<<32, 256, 0, stream>>>(wq, QM, TPART);
  k_tcast<<<8, 256, 0, stream>>>(TPART, TB);

  gemm256<1><<<512, 512, 0, stream>>>(FB, WVB, bv, HB, 1024, 4, 1024,
                                      nullptr, nullptr);
  k_logit<<<8192, 256, 0, stream>>>(FB, TB, LG);

  k_reduce<<<1, 1024, 0, stream>>>(LG, MS);
  k_ab<<<256, 256, 0, stream>>>(LG, MS, HB, outA, BBUF);
  k_c<<<1, 256, 0, stream>>>(BBUF, wfcc, bfcc, outC, outB);
}